// Round 1
// baseline (127.514 us; speedup 1.0000x reference)
//
#include <hip/hip_runtime.h>

// Problem constants (fixed shape from setup_inputs):
//   inputs: [M=4096, N=16384] fp32, targets: [M] int32
//   k = int(0.01 * (N-1)) = 163
#define M        4096
#define N        16384
#define K_SEL    163
#define DELTA_W  5.0f
#define NTHREADS 256
#define EPT      64            // elements per thread = N / NTHREADS
#define COPIES   16            // privatized histogram copies (atomic contention fix)

// Order-preserving float -> uint32 key (ascending float <-> ascending key)
__device__ __forceinline__ unsigned f2key(float x) {
    unsigned u = __float_as_uint(x);
    return (u & 0x80000000u) ? ~u : (u | 0x80000000u);
}
__device__ __forceinline__ float key2f(unsigned k) {
    unsigned u = (k & 0x80000000u) ? (k & 0x7FFFFFFFu) : ~k;
    return __uint_as_float(u);
}

// One block per row: radix-select the K_SEL-th largest (excluding target),
// then sum (v+1)^2 over the top-K_SEL set (exact under ties).
__global__ __launch_bounds__(NTHREADS) void row_topk_loss(
    const float* __restrict__ inp, const int* __restrict__ tgt,
    float* __restrict__ row_loss, float* __restrict__ out_atomic, int use_ws)
{
    const int row = blockIdx.x;
    const int tid = threadIdx.x;
    const float* rp = inp + (size_t)row * N;
    const int target = tgt[row];

    __shared__ unsigned cnt[256 * COPIES];   // 16 KiB
    __shared__ unsigned s_waveTot[NTHREADS / 64];
    __shared__ float    wpart[NTHREADS / 64];
    __shared__ unsigned s_prefix;
    __shared__ unsigned s_krem;

    // ---- load row once (coalesced float4), keep keys in registers ----
    unsigned kk[EPT];
    const float4* rp4 = reinterpret_cast<const float4*>(rp);
    #pragma unroll
    for (int i = 0; i < EPT / 4; ++i) {
        float4 v = rp4[i * NTHREADS + tid];
        int base = (i * NTHREADS + tid) * 4;
        unsigned k0 = f2key(v.x), k1 = f2key(v.y), k2 = f2key(v.z), k3 = f2key(v.w);
        // mask the positive: key 0 is the global minimum key, never in top-163
        if (base + 0 == target) k0 = 0u;
        if (base + 1 == target) k1 = 0u;
        if (base + 2 == target) k2 = 0u;
        if (base + 3 == target) k3 = 0u;
        kk[i*4+0] = k0; kk[i*4+1] = k1; kk[i*4+2] = k2; kk[i*4+3] = k3;
    }

    if (tid == 0) { s_prefix = 0u; s_krem = K_SEL; }

    const int lane  = tid & 63;
    const int wv    = tid >> 6;
    const int cslot = tid & (COPIES - 1);

    // ---- 4-pass MSB radix select (8 bits / pass) ----
    for (int pass = 0; pass < 4; ++pass) {
        #pragma unroll
        for (int i = 0; i < (256 * COPIES) / NTHREADS; ++i)
            cnt[i * NTHREADS + tid] = 0u;
        __syncthreads();

        const unsigned prefix = s_prefix;
        const unsigned krem   = s_krem;
        const int shift = 24 - 8 * pass;
        const int psh   = 32 - 8 * pass;   // prefix shift; only used when pass > 0

        if (pass == 0) {
            #pragma unroll
            for (int e = 0; e < EPT; ++e) {
                unsigned d = kk[e] >> 24;
                atomicAdd(&cnt[d * COPIES + cslot], 1u);
            }
        } else {
            #pragma unroll
            for (int e = 0; e < EPT; ++e) {
                if ((kk[e] >> psh) == prefix) {
                    unsigned d = (kk[e] >> shift) & 0xFFu;
                    atomicAdd(&cnt[d * COPIES + cslot], 1u);
                }
            }
        }
        __syncthreads();

        // total for bin 'tid'
        unsigned bc = 0;
        #pragma unroll
        for (int c = 0; c < COPIES; ++c) bc += cnt[tid * COPIES + c];

        // inclusive suffix-scan within this wave's 64-bin chunk (no LDS, no sync)
        unsigned suf = bc;
        #pragma unroll
        for (int off = 1; off < 64; off <<= 1) {
            unsigned o = __shfl_down(suf, off);
            suf += (lane + off < 64) ? o : 0u;
        }
        if (lane == 0) s_waveTot[wv] = suf;   // chunk total lives in lane 0
        __syncthreads();

        unsigned above_chunks = 0;
        for (int w = wv + 1; w < NTHREADS / 64; ++w) above_chunks += s_waveTot[w];
        unsigned S   = suf + above_chunks;    // # elements in bins >= tid
        unsigned abv = S - bc;                // # elements in bins >  tid
        if (abv < krem && S >= krem) {        // unique bin holds the krem-th largest
            s_prefix = (prefix << 8) | (unsigned)tid;
            s_krem   = krem - abv;
        }
        __syncthreads();
    }

    const unsigned tkey  = s_prefix;  // exact key of the K_SEL-th largest
    const unsigned kremf = s_krem;    // how many ties at tkey belong to top-K

    // ---- deterministic sum of (v+1)^2 over keys strictly greater than tkey ----
    float local = 0.0f;
    #pragma unroll
    for (int e = 0; e < EPT; ++e) {
        if (kk[e] > tkey) {
            float v = key2f(kk[e]) + 1.0f;
            local += v * v;
        }
    }
    #pragma unroll
    for (int off = 32; off > 0; off >>= 1)
        local += __shfl_down(local, off);
    if (lane == 0) wpart[wv] = local;
    __syncthreads();

    if (tid == 0) {
        float total = wpart[0] + wpart[1] + wpart[2] + wpart[3];
        float tv = key2f(tkey) + 1.0f;
        total += (float)kremf * tv * tv;          // tie fixup (exact: ties are equal values)
        float pos = rp[target];
        float pd  = pos - 1.0f;
        float loss = DELTA_W * pd * pd + total / (float)K_SEL;
        if (use_ws) row_loss[row] = loss;
        else        atomicAdd(out_atomic, loss / (float)M);
    }
}

__global__ __launch_bounds__(256) void final_reduce(
    const float* __restrict__ rl, float* __restrict__ out)
{
    int tid = threadIdx.x;
    float s = 0.0f;
    for (int i = tid; i < M; i += 256) s += rl[i];
    __shared__ float wp[4];
    int lane = tid & 63, wv = tid >> 6;
    #pragma unroll
    for (int off = 32; off > 0; off >>= 1) s += __shfl_down(s, off);
    if (lane == 0) wp[wv] = s;
    __syncthreads();
    if (tid == 0) out[0] = (wp[0] + wp[1] + wp[2] + wp[3]) / (float)M;
}

extern "C" void kernel_launch(void* const* d_in, const int* in_sizes, int n_in,
                              void* d_out, int out_size, void* d_ws, size_t ws_size,
                              hipStream_t stream) {
    const float* inp = (const float*)d_in[0];
    const int*   tgt = (const int*)d_in[1];
    float* out = (float*)d_out;
    float* row_loss = (float*)d_ws;

    const int use_ws = (ws_size >= (size_t)M * sizeof(float)) ? 1 : 0;
    if (!use_ws) {
        // fallback: accumulate atomically into d_out (init to 0 first)
        hipMemsetAsync(d_out, 0, sizeof(float), stream);
    }
    row_topk_loss<<<M, NTHREADS, 0, stream>>>(inp, tgt, row_loss, out, use_ws);
    if (use_ws) {
        final_reduce<<<1, 256, 0, stream>>>(row_loss, out);
    }
}